// Round 8
// baseline (961.240 us; speedup 1.0000x reference)
//
#include <hip/hip_runtime.h>

// Problem constants
#define BB      16384
#define IN_DIM  256
#define NE      32
#define H1D     64
#define H2D     256
#define H3D     128
#define NOUT    128

typedef __bf16 bf16_t;
typedef __bf16 bf16x8  __attribute__((ext_vector_type(8)));
typedef __bf16 bf16x4  __attribute__((ext_vector_type(4)));
typedef float  f32x4   __attribute__((ext_vector_type(4)));
typedef float  f32x16  __attribute__((ext_vector_type(16)));

// ---- workspace layout (bytes) ---- (total 15,810,560 B — proven r1–r7 budget)
#define OFF_WS  ((size_t)0)
#define OFF_BS  (OFF_WS + (size_t)NE*81920*2)            //  5242880
#define OFF_XS  (OFF_BS + (size_t)NE*640*4)              //  5324800
#define OFF_GT  (OFF_XS + (size_t)BB*IN_DIM*2)           // 13713408

// ---- prep: weights+biases -> frag-linear swizzled bf16 (verified r7) ----
__global__ void prep_w(const float* __restrict__ W1, const float* __restrict__ W2,
                       const float* __restrict__ W3, const float* __restrict__ W4,
                       const float* __restrict__ W5,
                       const float* __restrict__ b1, const float* __restrict__ b2,
                       const float* __restrict__ b3, const float* __restrict__ b4,
                       const float* __restrict__ b5,
                       bf16_t* __restrict__ Wswz, float* __restrict__ bswz)
{
    const int e   = blockIdx.x / 41;
    const int q   = blockIdx.x % 41;
    const int tid = threadIdx.x;

    if (q == 40) {
        for (int idx = tid; idx < 640; idx += 256) {
            const int ntc = idx >> 5;
            const int s   = idx & 31;
            const int h   = s >> 4, r = s & 15;
            const int fo  = (r & 3) + 8 * (r >> 2) + 4 * h;
            const float* bp; int off;
            if (ntc < 2)       { bp = b1 + e * H1D;  off = ntc * 32; }
            else if (ntc < 10) { bp = b2 + e * H2D;  off = (ntc - 2) * 32; }
            else if (ntc < 14) { bp = b3 + e * H3D;  off = (ntc - 10) * 32; }
            else if (ntc < 16) { bp = b4 + e * H1D;  off = (ntc - 14) * 32; }
            else               { bp = b5 + e * NOUT; off = (ntc - 16) * 32; }
            bswz[(size_t)e * 640 + idx] = bp[off + fo];
        }
        return;
    }

    const float* W; int K, N, nt, kt, base;
    if (q < 8)       { W = W1; K = 256; N = 64;  nt = q >> 2;        kt = q & 3;        base = 0; }
    else if (q < 16) { W = W2; K = 64;  N = 256; nt = q - 8;         kt = 0;            base = 16384; }
    else if (q < 32) { W = W3; K = 256; N = 128; nt = (q - 16) >> 2; kt = (q - 16) & 3; base = 32768; }
    else if (q < 36) { W = W4; K = 128; N = 64;  nt = (q - 32) >> 1; kt = (q - 32) & 1; base = 65536; }
    else             { W = W5; K = 64;  N = 128; nt = q - 36;        kt = 0;            base = 73728; }
    const int KC = K / 16;

    __shared__ float tile[64][36];
    const float* src = W + (size_t)e * K * N;
    {
        const int row = tid >> 2;
        const int c0  = (tid & 3) * 8;
        const float* sp = src + (size_t)(kt * 64 + row) * N + nt * 32 + c0;
        *(float4*)&tile[row][c0]     = *(const float4*)sp;
        *(float4*)&tile[row][c0 + 4] = *(const float4*)(sp + 4);
    }
    __syncthreads();
    {
        const int kc2  = tid >> 6;
        const int l    = tid & 63;
        const int krow = kc2 * 16 + (l >> 5) * 8;
        const int n    = l & 31;
        bf16x8 o = { (bf16_t)tile[krow + 0][n], (bf16_t)tile[krow + 1][n],
                     (bf16_t)tile[krow + 2][n], (bf16_t)tile[krow + 3][n],
                     (bf16_t)tile[krow + 4][n], (bf16_t)tile[krow + 5][n],
                     (bf16_t)tile[krow + 6][n], (bf16_t)tile[krow + 7][n] };
        *(bf16x8*)(Wswz + (size_t)e * 81920 + base
                   + ((size_t)(nt * KC + kt * 4 + kc2) * 64 + l) * 8) = o;
    }
}

// ---- prep: x -> frag-linear bf16 + gating softmax -> gT[e][b] (verified r7) ----
__global__ void prep_xg(const float* __restrict__ x, const float* __restrict__ Wg,
                        const float* __restrict__ bg,
                        bf16_t* __restrict__ xswz, float* __restrict__ gT)
{
    const int bt  = blockIdx.x;
    const int tid = threadIdx.x;
    const int r   = tid >> 3;
    const int seg = tid & 7;

    {
        const float* xp = x + ((size_t)bt * 32 + r) * IN_DIM + seg * 32;
        float xv[32];
#pragma unroll
        for (int i = 0; i < 8; i++) *(float4*)&xv[i * 4] = *(const float4*)(xp + i * 4);
#pragma unroll
        for (int kk = 0; kk < 4; kk++) {
            const int kc = seg * 2 + (kk >> 1);
            const int h  = kk & 1;
            const float* vv = &xv[(kk >> 1) * 16 + h * 8];
            bf16x8 o = { (bf16_t)vv[0], (bf16_t)vv[1], (bf16_t)vv[2], (bf16_t)vv[3],
                         (bf16_t)vv[4], (bf16_t)vv[5], (bf16_t)vv[6], (bf16_t)vv[7] };
            *(bf16x8*)(xswz + ((size_t)(bt * 16 + kc) * 64 + h * 32 + r) * 8) = o;
        }
    }
    {
        const float* xr = x + ((size_t)bt * 32 + r) * IN_DIM;
        float acc[4];
#pragma unroll
        for (int j = 0; j < 4; j++) acc[j] = bg[seg * 4 + j];
        for (int k = 0; k < IN_DIM; k++) {
            const float xk = xr[k];
#pragma unroll
            for (int j = 0; j < 4; j++) acc[j] = fmaf(xk, Wg[k * 32 + seg * 4 + j], acc[j]);
        }
        float mx = fmaxf(fmaxf(acc[0], acc[1]), fmaxf(acc[2], acc[3]));
#pragma unroll
        for (int off = 1; off < 8; off <<= 1) mx = fmaxf(mx, __shfl_xor(mx, off));
        float ex[4], sm = 0.f;
#pragma unroll
        for (int j = 0; j < 4; j++) { ex[j] = __expf(acc[j] - mx); sm += ex[j]; }
#pragma unroll
        for (int off = 1; off < 8; off <<= 1) sm += __shfl_xor(sm, off);
        const float rs = 1.f / sm;
#pragma unroll
        for (int j = 0; j < 4; j++)
            gT[(size_t)(seg * 4 + j) * BB + bt * 32 + r] = ex[j] * rs;
    }
}

// ---- relayout: D-tile -> 2 B-operand bf16x8 chunks (verified r7) ----
template<bool RELU>
__device__ __forceinline__ void relayout2(const f32x16& acc, const float* bs32,
                                          int half, bf16x8* out)
{
    float v[16];
    const f32x4* bq = (const f32x4*)(bs32 + half * 16);
#pragma unroll
    for (int qq = 0; qq < 4; qq++) {
        const f32x4 b4v = bq[qq];
#pragma unroll
        for (int i = 0; i < 4; i++) {
            float t = acc[qq * 4 + i] + b4v[i];
            v[qq * 4 + i] = RELU ? fmaxf(t, 0.f) : t;
        }
    }
#pragma unroll
    for (int c = 0; c < 2; c++) {
        float own[4], snd[4], rcv[4];
#pragma unroll
        for (int d = 0; d < 4; d++) {
            own[d] = half ? v[8 * c + 4 + d] : v[8 * c + d];
            snd[d] = half ? v[8 * c + d]     : v[8 * c + 4 + d];
        }
#pragma unroll
        for (int d = 0; d < 4; d++) rcv[d] = __shfl_xor(snd[d], 32, 64);
        float lo[4], hi[4];
#pragma unroll
        for (int d = 0; d < 4; d++) {
            lo[d] = half ? rcv[d] : own[d];
            hi[d] = half ? own[d] : rcv[d];
        }
        out[c] = (bf16x8){ (bf16_t)lo[0], (bf16_t)lo[1], (bf16_t)lo[2], (bf16_t)lo[3],
                           (bf16_t)hi[0], (bf16_t)hi[1], (bf16_t)hi[2], (bf16_t)hi[3] };
    }
}

// ---- register-output layer (verified r7) ----
template<int NT, int KS, bool RELU>
__device__ __forceinline__ void layerR(const bf16_t* __restrict__ wp,
                                       const float* __restrict__ bsc,
                                       const bf16x8* __restrict__ bin,
                                       bf16x8* __restrict__ bout,
                                       int lane, int half)
{
#pragma unroll
    for (int nt = 0; nt < NT; nt++) {
        f32x16 acc;
#pragma unroll
        for (int r = 0; r < 16; r++) acc[r] = 0.f;
#pragma unroll
        for (int kc = 0; kc < KS; kc++) {
            const bf16x8 wf = *(const bf16x8*)(wp + ((size_t)(nt * KS + kc) * 64 + lane) * 8);
            acc = __builtin_amdgcn_mfma_f32_32x32x16_bf16(wf, bin[kc], acc, 0, 0, 0);
        }
        relayout2<RELU>(acc, bsc + nt * 32, half, &bout[2 * nt]);
    }
}

// ---- LDS-output layer: bias+relu, pack D-frags into B-frag-layout LDS ----
// LDS elem (kc*64 + (batch + 32*khalf))*8 + j  == value of feature kc*16+8*khalf+j
template<int NT, int KS>
__device__ __forceinline__ void layer_lds(const bf16_t* __restrict__ wp,
                                          const float* __restrict__ bsc,
                                          const bf16x8* __restrict__ bin,
                                          bf16_t* __restrict__ ldst,
                                          int n0t, int lane, int half)
{
    const int batch = lane & 31;
#pragma unroll
    for (int nt = 0; nt < NT; nt++) {
        f32x16 acc;
#pragma unroll
        for (int r = 0; r < 16; r++) acc[r] = 0.f;
#pragma unroll
        for (int kc = 0; kc < KS; kc++) {
            const bf16x8 wf = *(const bf16x8*)(wp + ((size_t)((n0t + nt) * KS + kc) * 64 + lane) * 8);
            acc = __builtin_amdgcn_mfma_f32_32x32x16_bf16(wf, bin[kc], acc, 0, 0, 0);
        }
#pragma unroll
        for (int q = 0; q < 4; q++) {
            bf16x4 o;
#pragma unroll
            for (int i = 0; i < 4; i++) {
                const int r = q * 4 + i;
                const float v = acc[r] + bsc[(n0t + nt) * 32 + half * 16 + r];
                o[i] = (bf16_t)fmaxf(v, 0.f);
            }
            const int F0 = (n0t + nt) * 32 + 8 * q + 4 * half;  // features F0..F0+3
            const int kc = F0 >> 4;
            const int dl = batch + 32 * ((F0 >> 3) & 1);
            *(bf16x4*)(ldst + (size_t)kc * 512 + dl * 8 + (F0 & 7)) = o;
        }
    }
}

// ---- main: producer-consumer wave specialization ----
// Block 256 thr = 2 row-tiles x {A,B}. A: L1,L2 -> h2(LDS); L5 <- h4(LDS) -> oacc.
// B: L3,L4: h2(LDS) -> h4(LDS). 2 barriers/expert. Grid 256, 2 blocks/CU.
__global__ __launch_bounds__(256, 2) void moe_main(
    const bf16_t* __restrict__ Wswz, const float* __restrict__ bswz,
    const bf16_t* __restrict__ xswz, const float* __restrict__ gT,
    float* __restrict__ out)
{
    __shared__ __align__(16) bf16_t sH2[2][2][8192];  // [buf][tile][16kc*64*8] = 64 KB
    __shared__ __align__(16) bf16_t sH4[2][2048];     // [tile][4kc*64*8]       = 8 KB

    const int tid    = threadIdx.x;
    const int wave   = tid >> 6;
    const int lane   = tid & 63;
    const int lane31 = lane & 31;
    const int half   = lane >> 5;
    const int tl     = wave & 1;          // row-tile within block
    const bool isA   = (wave < 2);
    const int bt     = blockIdx.x * 2 + tl;
    const int b0w    = bt * 32;

    float oacc[4][16];                     // A-waves only (live)
#pragma unroll
    for (int nt = 0; nt < 4; nt++)
#pragma unroll
        for (int r = 0; r < 16; r++) oacc[nt][r] = 0.f;

    const bf16_t* xs = xswz + (size_t)bt * 8192;

    for (int e = 0; e <= NE; e++) {
        // ---- Phase 1 ----
        if (isA && e < NE) {
            const bf16_t* we = Wswz + (size_t)e * 81920;
            const float*  bs = bswz + (size_t)e * 640;
            // L1: x -> h1B (regs)
            bf16x8 xf[16];
#pragma unroll
            for (int kc = 0; kc < 16; kc++)
                xf[kc] = *(const bf16x8*)(xs + ((size_t)kc * 64 + lane) * 8);
            bf16x8 h1B[4];
            layerR<2, 16, true>(we, bs, xf, h1B, lane, half);
            // L2 in 2 halves -> sH2[e&1][tl]
            bf16_t* h2d = sH2[e & 1][tl];
            layer_lds<4, 4>(we + 16384, bs + 2 * 32, h1B, h2d, 0, lane, half);
            layer_lds<4, 4>(we + 16384, bs + 2 * 32, h1B, h2d, 4, lane, half);
        }
        if (!isA && e > 0) {
            const int ep = e - 1;
            const bf16_t* we = Wswz + (size_t)ep * 81920;
            const float*  bs = bswz + (size_t)ep * 640;
            // L3: h2(LDS) -> h3B (regs)
            const bf16_t* h2s = sH2[ep & 1][tl];
            bf16x8 h2B[16];
#pragma unroll
            for (int kc = 0; kc < 16; kc++)
                h2B[kc] = *(const bf16x8*)(h2s + ((size_t)kc * 64 + lane) * 8);
            bf16x8 h3B[8];
            layerR<4, 16, true>(we + 32768, bs + 10 * 32, h2B, h3B, lane, half);
            // L4: h3B -> sH4[tl]
            layer_lds<2, 8>(we + 65536, bs + 14 * 32, h3B, sH4[tl], 0, lane, half);
        }
        __syncthreads();
        // ---- Phase 2: A: L5(e-1) from sH4 ----
        if (isA && e > 0) {
            const int ep = e - 1;
            const bf16_t* wp5 = Wswz + (size_t)ep * 81920 + 73728;
            const float*  bs5 = bswz + (size_t)ep * 640 + 16 * 32;
            bf16x8 h4B[4];
#pragma unroll
            for (int kc = 0; kc < 4; kc++)
                h4B[kc] = *(const bf16x8*)(sH4[tl] + ((size_t)kc * 64 + lane) * 8);
            const float gv = gT[(size_t)ep * BB + b0w + lane31];
#pragma unroll
            for (int nt = 0; nt < 4; nt++) {
                f32x16 acc;
#pragma unroll
                for (int r = 0; r < 16; r++) acc[r] = 0.f;
#pragma unroll
                for (int kc = 0; kc < 4; kc++) {
                    const bf16x8 wf = *(const bf16x8*)(wp5 + ((size_t)(nt * 4 + kc) * 64 + lane) * 8);
                    acc = __builtin_amdgcn_mfma_f32_32x32x16_bf16(wf, h4B[kc], acc, 0, 0, 0);
                }
#pragma unroll
                for (int r = 0; r < 16; r++)
                    oacc[nt][r] += gv * (acc[r] + bs5[nt * 32 + half * 16 + r]);
            }
        }
        __syncthreads();
    }

    // ---- store (A-waves own their 32 rows exclusively) ----
    if (isA) {
        float* op = out + (size_t)(b0w + lane31) * NOUT;
#pragma unroll
        for (int nt = 0; nt < 4; nt++)
#pragma unroll
            for (int q = 0; q < 4; q++) {
                float4 v = { oacc[nt][q * 4 + 0], oacc[nt][q * 4 + 1],
                             oacc[nt][q * 4 + 2], oacc[nt][q * 4 + 3] };
                *(float4*)(op + nt * 32 + 8 * q + 4 * half) = v;
            }
    }
}

extern "C" void kernel_launch(void* const* d_in, const int* in_sizes, int n_in,
                              void* d_out, int out_size, void* d_ws, size_t ws_size,
                              hipStream_t stream)
{
    (void)in_sizes; (void)n_in; (void)out_size; (void)ws_size;
    const float* x  = (const float*)d_in[0];
    const float* Wg = (const float*)d_in[1];
    const float* bg = (const float*)d_in[2];
    const float* W1 = (const float*)d_in[3];
    const float* b1 = (const float*)d_in[4];
    const float* W2 = (const float*)d_in[5];
    const float* b2 = (const float*)d_in[6];
    const float* W3 = (const float*)d_in[7];
    const float* b3 = (const float*)d_in[8];
    const float* W4 = (const float*)d_in[9];
    const float* b4 = (const float*)d_in[10];
    const float* W5 = (const float*)d_in[11];
    const float* b5 = (const float*)d_in[12];

    char* ws = (char*)d_ws;
    bf16_t* Wswz = (bf16_t*)(ws + OFF_WS);
    float*  bswz = (float*)(ws + OFF_BS);
    bf16_t* xswz = (bf16_t*)(ws + OFF_XS);
    float*  gT   = (float*)(ws + OFF_GT);
    float*  out  = (float*)d_out;

    prep_w<<<dim3(NE * 41), dim3(256), 0, stream>>>(W1, W2, W3, W4, W5,
                                                    b1, b2, b3, b4, b5, Wswz, bswz);
    prep_xg<<<dim3(512), dim3(256), 0, stream>>>(x, Wg, bg, xswz, gT);
    moe_main<<<dim3(256), dim3(256), 0, stream>>>(Wswz, bswz, xswz, gT, out);
}